// Round 2
// baseline (1380.316 us; speedup 1.0000x reference)
//
#include <hip/hip_runtime.h>
#include <hip/hip_bf16.h>

#define NN 8
#define TT 192
#define HH 1024
#define DD 128
#define PP 4
#define TPP 48
#define EE 16384
#define NEDGE (EE + HH)      // 17408
#define BB (NN * TPP)        // 384
#define NOUT (NN * TT * DD)  // 196608

__device__ __forceinline__ float bf2f(__hip_bfloat16 h) { return __bfloat162float(h); }

// two bf16 packed in a uint (little-endian: element0 = low 16 bits) -> two floats
__device__ __forceinline__ void unpack2(unsigned int u, float& a, float& b) {
  union { unsigned int i; float f; } x, y;
  x.i = u << 16;
  y.i = u & 0xffff0000u;
  a = x.f; b = y.f;
}

// ---------------- small setup kernels ----------------

__global__ void k_deg(const int* __restrict__ edges, int* __restrict__ degE) {
  int e = blockIdx.x * 256 + threadIdx.x;
  if (e < EE) atomicAdd(&degE[edges[2 * e + 1]], 1);
}

__global__ void k_inv(const int* __restrict__ node_split, int* __restrict__ inv) {
  int i = blockIdx.x * 256 + threadIdx.x;
  if (i < HH) inv[node_split[i]] = i;
}

__global__ __launch_bounds__(1024) void k_scan(const int* __restrict__ degE,
                                               int* __restrict__ row_ptr) {
  __shared__ int tmp[HH];
  int t = threadIdx.x;
  tmp[t] = degE[t] + 1;  // +1 self loop
  __syncthreads();
  for (int off = 1; off < HH; off <<= 1) {
    int add = (t >= off) ? tmp[t - off] : 0;
    __syncthreads();
    tmp[t] += add;
    __syncthreads();
  }
  row_ptr[t + 1] = tmp[t];
  if (t == 0) row_ptr[0] = 0;
}

__global__ void k_scatter(const int* __restrict__ edges, const int* __restrict__ degE,
                          const int* __restrict__ row_ptr, const int* __restrict__ inv,
                          int* __restrict__ fill, int* __restrict__ csr_src,
                          float* __restrict__ csr_coef, float* __restrict__ Q) {
  int e = blockIdx.x * 256 + threadIdx.x;
  if (e >= NEDGE) return;
  int s, dt;
  if (e < EE) { s = edges[2 * e]; dt = edges[2 * e + 1]; }
  else        { s = dt = e - EE; }
  float ds = (float)(degE[s] + 1);
  float dd = (float)(degE[dt] + 1);
  float cf = rsqrtf(ds * dd);
  int pos = atomicAdd(&fill[dt], 1);
  int at = row_ptr[dt] + pos;
  csr_src[at] = s;
  csr_coef[at] = cf;
  int g = inv[dt] >> 8;  // group = position_in_node_split / 256
  atomicAdd(&Q[g * HH + s], cf * (1.0f / 256.0f));
}

// transpose timeconv_w (o, c, k) -> twT[(c*4+k)*128 + o]
__global__ void k_twt(const float* __restrict__ tw, float* __restrict__ twT) {
  int i = blockIdx.x * 256 + threadIdx.x;  // 65536 = 128*128*4
  int o = i >> 9, ck = i & 511;
  twT[ck * DD + o] = tw[i];
}

// time embedding: per (n,t') 128-wide conv over 512 (c,k) terms.
// Writes fp32 time_emb (ws) and the fp32 time_rep output (replicated x4).
__global__ __launch_bounds__(128) void k_time(const int* __restrict__ xm,
                                              const float* __restrict__ hour_emb,
                                              const float* __restrict__ wday_emb,
                                              const float* __restrict__ twT,
                                              const float* __restrict__ tcb,
                                              float* __restrict__ time_emb,
                                              float* __restrict__ out2) {
  int b = blockIdx.x;
  int n = b / TPP, tp = b % TPP;
  int o = threadIdx.x;
  __shared__ float sL[512];
  for (int k = 0; k < 4; ++k) {
    int t = tp * 4 + k;
    int wd = xm[(n * TT + t) * 2 + 0];
    int hr = xm[(n * TT + t) * 2 + 1];
    sL[o * 4 + k] = hour_emb[hr * DD + o] + wday_emb[wd * DD + o];
  }
  __syncthreads();
  float acc = tcb[o];
  for (int j = 0; j < 512; ++j) acc = fmaf(sL[j], twT[j * DD + o], acc);
  time_emb[b * DD + o] = acc;
  size_t base = ((size_t)n * TT + tp * 4) * DD + o;
  out2[base] = acc;
  out2[base + DD] = acc;
  out2[base + 2 * DD] = acc;
  out2[base + 3 * DD] = acc;
}

// ---------------- the big fused kernel ----------------
// Per block: one b (= n*48+t'), 32 rows (nodes h0..h0+31).
// Phase 1: gather neighbors via CSR, recompute tv on the fly (4-tap conv of x),
//          weighted-sum into agg row (fp32 acc), store bf16 aggT[d][r] in LDS.
// Phase 2: 32x128 @ 128x128 matmul vs LDS-staged bf16 W1, 4x4 register tile.
// Phase 3: +b1, relu, Q-weighted accumulate into y[b][g][o] (LDS then global atomics).
__global__ __launch_bounds__(256) void k_main(
    const float* __restrict__ x, const float* __restrict__ tcw,
    const float* __restrict__ tcb, const float* __restrict__ W1,
    const float* __restrict__ b1, const int* __restrict__ row_ptr,
    const int* __restrict__ csr_src, const float* __restrict__ csr_coef,
    const float* __restrict__ Q, float* __restrict__ y) {
  __shared__ __align__(16) __hip_bfloat16 w1L[DD * DD];  // 32 KB, row-major [d][o]
  __shared__ __align__(16) __hip_bfloat16 aggT[DD * 40]; // [d][r], stride 40, 10 KB
  __shared__ __align__(16) float x4[HH * 4];             // [s][k], 16 KB
  __shared__ float yL[4 * DD];                           // 2 KB   (total 60 KB)
  int tid = threadIdx.x;
  int b = blockIdx.y;
  int h0 = blockIdx.x * 32;
  int n = b / TPP, tp = b % TPP;
  const float* xb = x + ((size_t)n * TT + tp * 4) * HH;

  for (int i = tid; i < DD * DD; i += 256) w1L[i] = __float2bfloat16(W1[i]);
  for (int i = tid; i < 4096; i += 256) {
    int s = i & 1023, k = i >> 10;      // k*1024+s == i, so read is coalesced
    x4[s * 4 + k] = xb[i];
  }
  for (int i = tid; i < 512; i += 256) yL[i] = 0.f;

  int d = tid & 127;
  float tw0 = tcw[d * 4 + 0];
  float tw1 = tcw[d * 4 + 1];
  float tw2 = tcw[d * 4 + 2];
  float tw3 = tcw[d * 4 + 3];
  float tbv = tcb[d];
  __syncthreads();

  const float4* x4v = (const float4*)x4;
  for (int rs = 0; rs < 16; ++rs) {
    int r = rs * 2 + (tid >> 7);  // wave-uniform row
    int h = h0 + r;
    int j0 = row_ptr[h], j1 = row_ptr[h + 1];
    float acc = 0.f;
    for (int j = j0; j < j1; ++j) {
      int s = csr_src[j];
      float cf = csr_coef[j];
      float4 a = x4v[s];
      float conv = tbv;
      conv = fmaf(a.x, tw0, conv);
      conv = fmaf(a.y, tw1, conv);
      conv = fmaf(a.z, tw2, conv);
      conv = fmaf(a.w, tw3, conv);
      acc = fmaf(cf, conv, acc);
    }
    aggT[d * 40 + r] = __float2bfloat16(acc);
  }
  __syncthreads();

  int og = tid & 31, rg = tid >> 5;
  int o0 = og * 4, r0 = rg * 4;
  float acc4[4][4];
#pragma unroll
  for (int i = 0; i < 4; ++i)
#pragma unroll
    for (int jj = 0; jj < 4; ++jj) acc4[i][jj] = 0.f;

  const unsigned int* w1u = (const unsigned int*)w1L;
  const unsigned int* agu = (const unsigned int*)aggT;
#pragma unroll 4
  for (int dd2 = 0; dd2 < DD; ++dd2) {
    unsigned int uw0 = w1u[(dd2 * DD + o0) >> 1];
    unsigned int uw1 = w1u[((dd2 * DD + o0) >> 1) + 1];
    float w0, w1v, w2, w3;
    unpack2(uw0, w0, w1v);
    unpack2(uw1, w2, w3);
    unsigned int ua0 = agu[(dd2 * 40 + r0) >> 1];
    unsigned int ua1 = agu[((dd2 * 40 + r0) >> 1) + 1];
    float a0, a1, a2, a3;
    unpack2(ua0, a0, a1);
    unpack2(ua1, a2, a3);
    acc4[0][0] = fmaf(a0, w0, acc4[0][0]);
    acc4[0][1] = fmaf(a0, w1v, acc4[0][1]);
    acc4[0][2] = fmaf(a0, w2, acc4[0][2]);
    acc4[0][3] = fmaf(a0, w3, acc4[0][3]);
    acc4[1][0] = fmaf(a1, w0, acc4[1][0]);
    acc4[1][1] = fmaf(a1, w1v, acc4[1][1]);
    acc4[1][2] = fmaf(a1, w2, acc4[1][2]);
    acc4[1][3] = fmaf(a1, w3, acc4[1][3]);
    acc4[2][0] = fmaf(a2, w0, acc4[2][0]);
    acc4[2][1] = fmaf(a2, w1v, acc4[2][1]);
    acc4[2][2] = fmaf(a2, w2, acc4[2][2]);
    acc4[2][3] = fmaf(a2, w3, acc4[2][3]);
    acc4[3][0] = fmaf(a3, w0, acc4[3][0]);
    acc4[3][1] = fmaf(a3, w1v, acc4[3][1]);
    acc4[3][2] = fmaf(a3, w2, acc4[3][2]);
    acc4[3][3] = fmaf(a3, w3, acc4[3][3]);
  }

  float bo0 = b1[o0 + 0];
  float bo1 = b1[o0 + 1];
  float bo2 = b1[o0 + 2];
  float bo3 = b1[o0 + 3];
  float vv[4][4];
#pragma unroll
  for (int i = 0; i < 4; ++i) {
    vv[i][0] = fmaxf(acc4[i][0] + bo0, 0.f);
    vv[i][1] = fmaxf(acc4[i][1] + bo1, 0.f);
    vv[i][2] = fmaxf(acc4[i][2] + bo2, 0.f);
    vv[i][3] = fmaxf(acc4[i][3] + bo3, 0.f);
  }
  float qv[4][4];  // [g][i]
#pragma unroll
  for (int g = 0; g < 4; ++g)
#pragma unroll
    for (int i = 0; i < 4; ++i) qv[g][i] = Q[g * HH + h0 + r0 + i];

#pragma unroll
  for (int g = 0; g < 4; ++g)
#pragma unroll
    for (int jo = 0; jo < 4; ++jo) {
      float s = qv[g][0] * vv[0][jo] + qv[g][1] * vv[1][jo] +
                qv[g][2] * vv[2][jo] + qv[g][3] * vv[3][jo];
      atomicAdd(&yL[g * DD + o0 + jo], s);
    }
  __syncthreads();
  for (int i = tid; i < 512; i += 256) atomicAdd(&y[(size_t)b * 512 + i], yL[i]);
}

// epilogue: z = y @ W2 + b2; out = z + time_emb
__global__ __launch_bounds__(128) void k_out(const float* __restrict__ y,
                                             const float* __restrict__ W2,
                                             const float* __restrict__ b2,
                                             const float* __restrict__ time_emb,
                                             float* __restrict__ out1) {
  int bg = blockIdx.x;
  int b = bg >> 2, g = bg & 3;
  int n = b / TPP, tp = b % TPP;
  int o = threadIdx.x;
  __shared__ float yLoc[DD];
  yLoc[o] = y[(size_t)b * 512 + g * DD + o];
  __syncthreads();
  float acc = b2[o];
  for (int dd2 = 0; dd2 < DD; ++dd2) acc = fmaf(yLoc[dd2], W2[dd2 * DD + o], acc);
  float outv = acc + time_emb[b * DD + o];
  out1[((size_t)n * TT + tp * 4 + g) * DD + o] = outv;
}

extern "C" void kernel_launch(void* const* d_in, const int* in_sizes, int n_in,
                              void* d_out, int out_size, void* d_ws, size_t ws_size,
                              hipStream_t stream) {
  const float* x = (const float*)d_in[0];
  const int* xm = (const int*)d_in[1];
  const int* edges = (const int*)d_in[2];
  const int* node_split = (const int*)d_in[3];
  const float* hour_emb = (const float*)d_in[4];
  const float* wday_emb = (const float*)d_in[5];
  const float* timeconv_w = (const float*)d_in[6];
  const float* timeconv_b = (const float*)d_in[7];
  const float* tcw = (const float*)d_in[8];
  const float* tcb = (const float*)d_in[9];
  const float* W1 = (const float*)d_in[10];
  const float* b1 = (const float*)d_in[11];
  const float* W2 = (const float*)d_in[12];
  const float* b2 = (const float*)d_in[13];
  float* out = (float*)d_out;

  char* w = (char*)d_ws;
  // zeroed block: degE | fill | Q | y
  int* degE = (int*)(w + 0);            //   4096 B
  int* fill = (int*)(w + 4096);         //   4096 B
  float* Q = (float*)(w + 8192);        //  16384 B
  float* yv = (float*)(w + 24576);      // 786432 B
  size_t zbytes = 811008;
  int* row_ptr = (int*)(w + 811008);    //   4100 B (padded)
  int* inv = (int*)(w + 815360);        //   4096 B
  int* csr_src = (int*)(w + 819456);    //  69632 B
  float* csr_coef = (float*)(w + 889088);   // 69632 B
  float* twT = (float*)(w + 958720);        // 262144 B
  float* time_emb = (float*)(w + 1220864);  // 196608 B  (total 1417472 B)

  hipMemsetAsync(d_ws, 0, zbytes, stream);
  k_deg<<<64, 256, 0, stream>>>(edges, degE);
  k_inv<<<4, 256, 0, stream>>>(node_split, inv);
  k_scan<<<1, 1024, 0, stream>>>(degE, row_ptr);
  k_scatter<<<68, 256, 0, stream>>>(edges, degE, row_ptr, inv, fill, csr_src, csr_coef, Q);
  k_twt<<<256, 256, 0, stream>>>(timeconv_w, twT);
  k_time<<<BB, 128, 0, stream>>>(xm, hour_emb, wday_emb, twT, timeconv_b, time_emb,
                                 out + NOUT);
  dim3 gmain(32, BB);
  k_main<<<gmain, 256, 0, stream>>>(x, tcw, tcb, W1, b1, row_ptr, csr_src, csr_coef, Q,
                                    yv);
  k_out<<<BB * 4, 128, 0, stream>>>(yv, W2, b2, time_emb, out);
}

// Round 3
// 455.736 us; speedup vs baseline: 3.0288x; 3.0288x over previous
//
#include <hip/hip_runtime.h>
#include <hip/hip_bf16.h>

#define NN 8
#define TT 192
#define HH 1024
#define DD 128
#define TPP 48
#define EE 16384
#define NEDGE (EE + HH)      // 17408
#define BB (NN * TPP)        // 384
#define NOUT (NN * TT * DD)  // 196608

typedef short bf16x8 __attribute__((ext_vector_type(8)));
typedef float f32x4 __attribute__((ext_vector_type(4)));

// ---------------- small setup kernels ----------------

__global__ void k_deg(const int* __restrict__ edges, int* __restrict__ degE) {
  int e = blockIdx.x * 256 + threadIdx.x;
  if (e < EE) atomicAdd(&degE[edges[2 * e + 1]], 1);
}

__global__ void k_inv(const int* __restrict__ node_split, int* __restrict__ inv) {
  int i = blockIdx.x * 256 + threadIdx.x;
  if (i < HH) inv[node_split[i]] = i;
}

__global__ __launch_bounds__(1024) void k_scan(const int* __restrict__ degE,
                                               int* __restrict__ row_ptr) {
  __shared__ int tmp[HH];
  int t = threadIdx.x;
  tmp[t] = degE[t] + 1;  // +1 self loop
  __syncthreads();
  for (int off = 1; off < HH; off <<= 1) {
    int add = (t >= off) ? tmp[t - off] : 0;
    __syncthreads();
    tmp[t] += add;
    __syncthreads();
  }
  row_ptr[t + 1] = tmp[t];
  if (t == 0) row_ptr[0] = 0;
}

__global__ void k_scatter(const int* __restrict__ edges, const int* __restrict__ degE,
                          const int* __restrict__ row_ptr, const int* __restrict__ inv,
                          int* __restrict__ fill, int* __restrict__ csr_src,
                          float* __restrict__ csr_coef, float* __restrict__ Q) {
  int e = blockIdx.x * 256 + threadIdx.x;
  if (e >= NEDGE) return;
  int s, dt;
  if (e < EE) { s = edges[2 * e]; dt = edges[2 * e + 1]; }
  else        { s = dt = e - EE; }
  float ds = (float)(degE[s] + 1);
  float dd = (float)(degE[dt] + 1);
  float cf = rsqrtf(ds * dd);
  int pos = atomicAdd(&fill[dt], 1);
  int at = row_ptr[dt] + pos;
  csr_src[at] = s;
  csr_coef[at] = cf;
  int g = inv[dt] >> 8;  // group = position_in_node_split / 256
  atomicAdd(&Q[g * HH + s], cf * (1.0f / 256.0f));
}

// transpose timeconv_w (o, c, k) -> twT[(c*4+k)*128 + o]
__global__ void k_twt(const float* __restrict__ tw, float* __restrict__ twT) {
  int i = blockIdx.x * 256 + threadIdx.x;  // 65536 = 128*128*4
  int o = i >> 9, ck = i & 511;
  twT[ck * DD + o] = tw[i];
}

// W1 (d,o) fp32 -> w1t bf16 [o][d] (n-major, k contiguous)
__global__ void k_prep(const float* __restrict__ W1, __hip_bfloat16* __restrict__ w1t) {
  int i = blockIdx.x * 256 + threadIdx.x;  // 16384
  int n = i >> 7, k = i & 127;
  w1t[i] = __float2bfloat16(W1[k * DD + n]);
}

// time embedding: 2 b's per block, 4-way independent accumulation.
__global__ __launch_bounds__(256) void k_time(const int* __restrict__ xm,
                                              const float* __restrict__ hour_emb,
                                              const float* __restrict__ wday_emb,
                                              const float* __restrict__ twT,
                                              const float* __restrict__ tcb,
                                              float* __restrict__ time_emb,
                                              float* __restrict__ out2) {
  int tid = threadIdx.x;
  int half = tid >> 7, o = tid & 127;
  int b = blockIdx.x * 2 + half;
  int n = b / TPP, tp = b % TPP;
  __shared__ float sL[2][512];
  for (int k = 0; k < 4; ++k) {
    int t = tp * 4 + k;
    int wd = xm[(n * TT + t) * 2 + 0];
    int hr = xm[(n * TT + t) * 2 + 1];
    sL[half][o * 4 + k] = hour_emb[hr * DD + o] + wday_emb[wd * DD + o];
  }
  __syncthreads();
  float a0 = tcb[o], a1 = 0.f, a2 = 0.f, a3 = 0.f;
  for (int j = 0; j < 512; j += 4) {
    a0 = fmaf(sL[half][j + 0], twT[(j + 0) * DD + o], a0);
    a1 = fmaf(sL[half][j + 1], twT[(j + 1) * DD + o], a1);
    a2 = fmaf(sL[half][j + 2], twT[(j + 2) * DD + o], a2);
    a3 = fmaf(sL[half][j + 3], twT[(j + 3) * DD + o], a3);
  }
  float acc = (a0 + a1) + (a2 + a3);
  time_emb[b * DD + o] = acc;
  size_t base = ((size_t)n * TT + tp * 4) * DD + o;
  out2[base] = acc;
  out2[base + DD] = acc;
  out2[base + 2 * DD] = acc;
  out2[base + 3 * DD] = acc;
}

// ---------------- fused xbar-gather + conv-expand + MFMA GEMM ----------------
// Block: one b, 64 h-rows. LDS: W1T swizzled [0:32K), agg swizzled [32K:48K)
// (x-patch bf16 overlays [32K:40K) during phase A). 52.5 KB -> 3 blocks/CU.
__global__ __launch_bounds__(256, 3) void k_gemm(
    const float* __restrict__ x, const float* __restrict__ tcw,
    const float* __restrict__ tcb, const __hip_bfloat16* __restrict__ w1t,
    const float* __restrict__ bias1, const int* __restrict__ row_ptr,
    const int* __restrict__ csr_src, const float* __restrict__ csr_coef,
    const float* __restrict__ Q, float* __restrict__ y) {
  __shared__ __align__(16) char uni[49152];
  __shared__ float xbarL[64 * 5];
  __shared__ float yL[512];
  int tid = threadIdx.x;
  int h0 = blockIdx.x * 64;
  int b = blockIdx.y;
  int n_ = b / TPP, tp = b % TPP;

  // stage: x-patch (bf16, [s][k]) at uni+32768; W1T swizzled at uni[0:32768)
  const float* xb = x + ((size_t)n_ * TT + tp * 4) * HH;
  __hip_bfloat16* xp = (__hip_bfloat16*)(uni + 32768);
  for (int i = tid; i < 4096; i += 256) {
    int s = i & 1023, k = i >> 10;  // i = k*1024 + s, coalesced read
    xp[s * 4 + k] = __float2bfloat16(xb[i]);
  }
  const uint4* w1src = (const uint4*)w1t;
  for (int gidx = tid; gidx < 2048; gidx += 256) {
    int nr = gidx >> 4, gg = gidx & 15;
    uint4 v = w1src[gidx];
    *(uint4*)(uni + nr * 256 + ((gg ^ (nr & 7)) * 16)) = v;
  }
  for (int i = tid; i < 320; i += 256) xbarL[i] = 0.f;
  for (int i = tid; i < 512; i += 256) yL[i] = 0.f;
  __syncthreads();

  // phase A: xbar[r][0..3] = sum_nbr cf*x4[s], xbar[r][4] = sum_nbr cf
  {
    int r = tid & 63, part = tid >> 6;
    int h = h0 + r;
    int j0 = row_ptr[h], j1 = row_ptr[h + 1];
    float a0 = 0.f, a1 = 0.f, a2 = 0.f, a3 = 0.f, acs = 0.f;
    for (int j = j0 + part; j < j1; j += 4) {
      int s = csr_src[j];
      float cf = csr_coef[j];
      uint2 u = *(const uint2*)(uni + 32768 + s * 8);
      union { unsigned i; float f; } t0, t1, t2, t3;
      t0.i = u.x << 16;
      t1.i = u.x & 0xffff0000u;
      t2.i = u.y << 16;
      t3.i = u.y & 0xffff0000u;
      a0 = fmaf(cf, t0.f, a0);
      a1 = fmaf(cf, t1.f, a1);
      a2 = fmaf(cf, t2.f, a2);
      a3 = fmaf(cf, t3.f, a3);
      acs += cf;
    }
    atomicAdd(&xbarL[r * 5 + 0], a0);
    atomicAdd(&xbarL[r * 5 + 1], a1);
    atomicAdd(&xbarL[r * 5 + 2], a2);
    atomicAdd(&xbarL[r * 5 + 3], a3);
    atomicAdd(&xbarL[r * 5 + 4], acs);
  }
  __syncthreads();

  // phase A2: agg[row][d] = cs*tcb[d] + sum_k xbar[row][k]*tcw[d][k], bf16 swizzled
  for (int it = 0; it < 16; ++it) {
    int p = it * 256 + tid;
    int row = p >> 6, dp = p & 63;
    int d0 = dp * 2;
    float xr0 = xbarL[row * 5 + 0], xr1 = xbarL[row * 5 + 1];
    float xr2 = xbarL[row * 5 + 2], xr3 = xbarL[row * 5 + 3];
    float xcs = xbarL[row * 5 + 4];
    float v0 = xcs * tcb[d0];
    v0 = fmaf(xr0, tcw[d0 * 4 + 0], v0);
    v0 = fmaf(xr1, tcw[d0 * 4 + 1], v0);
    v0 = fmaf(xr2, tcw[d0 * 4 + 2], v0);
    v0 = fmaf(xr3, tcw[d0 * 4 + 3], v0);
    float v1 = xcs * tcb[d0 + 1];
    v1 = fmaf(xr0, tcw[(d0 + 1) * 4 + 0], v1);
    v1 = fmaf(xr1, tcw[(d0 + 1) * 4 + 1], v1);
    v1 = fmaf(xr2, tcw[(d0 + 1) * 4 + 2], v1);
    v1 = fmaf(xr3, tcw[(d0 + 1) * 4 + 3], v1);
    union { __hip_bfloat16 h[2]; unsigned u; } pk;
    pk.h[0] = __float2bfloat16(v0);
    pk.h[1] = __float2bfloat16(v1);
    int gg = d0 >> 3;
    *(unsigned*)(uni + 32768 + row * 256 + ((gg ^ (row & 7)) * 16) + (d0 & 7) * 2) = pk.u;
  }
  __syncthreads();

  // GEMM phase: wave w -> m-tiles {mp,mp+1}, n-tiles {np..np+3}
  int lane = tid & 63;
  int w = tid >> 6;
  int colq = lane & 15, quad = lane >> 4;
  int mp = (w >> 1) * 2;
  int np = (w & 1) * 4;
  f32x4 acc[2][4];
#pragma unroll
  for (int im = 0; im < 2; ++im)
#pragma unroll
    for (int jn = 0; jn < 4; ++jn) acc[im][jn] = (f32x4){0.f, 0.f, 0.f, 0.f};

#pragma unroll
  for (int kc = 0; kc < 4; ++kc) {
    bf16x8 afr[2], bfr[4];
#pragma unroll
    for (int im = 0; im < 2; ++im) {
      int row = (mp + im) * 16 + colq;
      afr[im] = *(const bf16x8*)(uni + 32768 + row * 256 + (((kc * 4 + quad) ^ (row & 7)) * 16));
    }
#pragma unroll
    for (int jn = 0; jn < 4; ++jn) {
      int nr = (np + jn) * 16 + colq;
      bfr[jn] = *(const bf16x8*)(uni + nr * 256 + (((kc * 4 + quad) ^ (nr & 7)) * 16));
    }
#pragma unroll
    for (int im = 0; im < 2; ++im)
#pragma unroll
      for (int jn = 0; jn < 4; ++jn)
        acc[im][jn] = __builtin_amdgcn_mfma_f32_16x16x32_bf16(afr[im], bfr[jn],
                                                              acc[im][jn], 0, 0, 0);
  }

  // epilogue: relu(+b1), Q-weighted reduce over rows into yL
#pragma unroll
  for (int im = 0; im < 2; ++im) {
    int rbase = (mp + im) * 16 + quad * 4;  // tile-local rows rbase..rbase+3
    float qg[4][4];
#pragma unroll
    for (int g = 0; g < 4; ++g)
#pragma unroll
      for (int reg = 0; reg < 4; ++reg) qg[g][reg] = Q[g * HH + h0 + rbase + reg];
#pragma unroll
    for (int jn = 0; jn < 4; ++jn) {
      int nr = (np + jn) * 16 + colq;
      float bo = bias1[nr];
      f32x4 c = acc[im][jn];
      float v0 = fmaxf(c[0] + bo, 0.f);
      float v1 = fmaxf(c[1] + bo, 0.f);
      float v2 = fmaxf(c[2] + bo, 0.f);
      float v3 = fmaxf(c[3] + bo, 0.f);
#pragma unroll
      for (int g = 0; g < 4; ++g) {
        float pg = qg[g][0] * v0 + qg[g][1] * v1 + qg[g][2] * v2 + qg[g][3] * v3;
        atomicAdd(&yL[g * DD + nr], pg);
      }
    }
  }
  __syncthreads();
  for (int i = tid; i < 512; i += 256) atomicAdd(&y[(size_t)b * 512 + i], yL[i]);
}

// epilogue: z = y @ W2 + b2; out = z + time_emb
__global__ __launch_bounds__(128) void k_out(const float* __restrict__ y,
                                             const float* __restrict__ W2,
                                             const float* __restrict__ b2,
                                             const float* __restrict__ time_emb,
                                             float* __restrict__ out1) {
  int bg = blockIdx.x;
  int b = bg >> 2, g = bg & 3;
  int n = b / TPP, tp = b % TPP;
  int o = threadIdx.x;
  __shared__ float yLoc[DD];
  yLoc[o] = y[(size_t)b * 512 + g * DD + o];
  __syncthreads();
  float a0 = b2[o], a1 = 0.f, a2 = 0.f, a3 = 0.f;
  for (int d = 0; d < DD; d += 4) {
    a0 = fmaf(yLoc[d + 0], W2[(d + 0) * DD + o], a0);
    a1 = fmaf(yLoc[d + 1], W2[(d + 1) * DD + o], a1);
    a2 = fmaf(yLoc[d + 2], W2[(d + 2) * DD + o], a2);
    a3 = fmaf(yLoc[d + 3], W2[(d + 3) * DD + o], a3);
  }
  float outv = (a0 + a1) + (a2 + a3) + time_emb[b * DD + o];
  out1[((size_t)n * TT + tp * 4 + g) * DD + o] = outv;
}

extern "C" void kernel_launch(void* const* d_in, const int* in_sizes, int n_in,
                              void* d_out, int out_size, void* d_ws, size_t ws_size,
                              hipStream_t stream) {
  const float* x = (const float*)d_in[0];
  const int* xm = (const int*)d_in[1];
  const int* edges = (const int*)d_in[2];
  const int* node_split = (const int*)d_in[3];
  const float* hour_emb = (const float*)d_in[4];
  const float* wday_emb = (const float*)d_in[5];
  const float* timeconv_w = (const float*)d_in[6];
  const float* timeconv_b = (const float*)d_in[7];
  const float* tcw = (const float*)d_in[8];
  const float* tcb = (const float*)d_in[9];
  const float* W1 = (const float*)d_in[10];
  const float* b1 = (const float*)d_in[11];
  const float* W2 = (const float*)d_in[12];
  const float* b2 = (const float*)d_in[13];
  float* out = (float*)d_out;

  char* w = (char*)d_ws;
  int* degE = (int*)(w + 0);                //   4096 B (zeroed)
  int* fill = (int*)(w + 4096);             //   4096 B (zeroed)
  float* Q = (float*)(w + 8192);            //  16384 B (zeroed)
  float* yv = (float*)(w + 24576);          // 786432 B (zeroed)
  size_t zbytes = 811008;
  int* row_ptr = (int*)(w + 811008);        //   4352 B
  int* inv = (int*)(w + 815360);            //   4096 B
  int* csr_src = (int*)(w + 819456);        //  69632 B
  float* csr_coef = (float*)(w + 889088);   //  69632 B
  float* twT = (float*)(w + 958720);        // 262144 B
  float* time_emb = (float*)(w + 1220864);  // 196608 B
  __hip_bfloat16* w1t = (__hip_bfloat16*)(w + 1417472);  // 32768 B (total 1450240)

  hipMemsetAsync(d_ws, 0, zbytes, stream);
  k_deg<<<64, 256, 0, stream>>>(edges, degE);
  k_inv<<<4, 256, 0, stream>>>(node_split, inv);
  k_scan<<<1, 1024, 0, stream>>>(degE, row_ptr);
  k_scatter<<<68, 256, 0, stream>>>(edges, degE, row_ptr, inv, fill, csr_src, csr_coef, Q);
  k_twt<<<256, 256, 0, stream>>>(timeconv_w, twT);
  k_prep<<<64, 256, 0, stream>>>(W1, w1t);
  k_time<<<BB / 2, 256, 0, stream>>>(xm, hour_emb, wday_emb, twT, timeconv_b, time_emb,
                                     out + NOUT);
  dim3 gmain(16, BB);
  k_gemm<<<gmain, 256, 0, stream>>>(x, tcw, tcb, w1t, b1, row_ptr, csr_src, csr_coef, Q,
                                    yv);
  k_out<<<BB * 4, 128, 0, stream>>>(yv, W2, b2, time_emb, out);
}

// Round 4
// 199.803 us; speedup vs baseline: 6.9084x; 2.2809x over previous
//
#include <hip/hip_runtime.h>
#include <hip/hip_bf16.h>

#define NN 8
#define TT 192
#define HH 1024
#define DD 128
#define TPP 48
#define EE 16384
#define NEDGE (EE + HH)      // 17408
#define BB (NN * TPP)        // 384
#define NOUT (NN * TT * DD)  // 196608

typedef short bf16x8 __attribute__((ext_vector_type(8)));
typedef float f32x4 __attribute__((ext_vector_type(4)));

__device__ __forceinline__ float bf2f(__hip_bfloat16 h) { return __bfloat162float(h); }

// ---------------- setup: degree + node_split inverse + W1 pre-swizzle ----------------
__global__ void k_setup(const int* __restrict__ edges, int* __restrict__ degE,
                        const int* __restrict__ node_split, int* __restrict__ inv,
                        const float* __restrict__ W1, __hip_bfloat16* __restrict__ w1sw) {
  int i = blockIdx.x * 256 + threadIdx.x;
  if (i < EE) atomicAdd(&degE[edges[2 * i + 1]], 1);
  if (i < HH) inv[node_split[i]] = i;
  if (i < DD * DD) {
    int n = i >> 7, k = i & 127;  // W1T[n][k] = W1[k][n]
    int gg = k >> 3;
    int dstb = n * 256 + ((gg ^ (n & 7)) * 16) + (k & 7) * 2;  // swizzled byte addr
    w1sw[dstb >> 1] = __float2bfloat16(W1[k * DD + n]);
  }
}

__global__ __launch_bounds__(1024) void k_scan(const int* __restrict__ degE,
                                               int* __restrict__ row_ptr) {
  __shared__ int tmp[HH];
  int t = threadIdx.x;
  tmp[t] = degE[t] + 1;  // +1 self loop
  __syncthreads();
  for (int off = 1; off < HH; off <<= 1) {
    int add = (t >= off) ? tmp[t - off] : 0;
    __syncthreads();
    tmp[t] += add;
    __syncthreads();
  }
  row_ptr[t + 1] = tmp[t];
  if (t == 0) row_ptr[0] = 0;
}

__global__ void k_scatter(const int* __restrict__ edges, const int* __restrict__ degE,
                          const int* __restrict__ row_ptr, const int* __restrict__ inv,
                          int* __restrict__ fill, int* __restrict__ csr_src,
                          float* __restrict__ csr_coef, float* __restrict__ Q) {
  int e = blockIdx.x * 256 + threadIdx.x;
  if (e >= NEDGE) return;
  int s, dt;
  if (e < EE) { s = edges[2 * e]; dt = edges[2 * e + 1]; }
  else        { s = dt = e - EE; }
  float ds = (float)(degE[s] + 1);
  float dd = (float)(degE[dt] + 1);
  float cf = rsqrtf(ds * dd);
  int pos = atomicAdd(&fill[dt], 1);
  int at = row_ptr[dt] + pos;
  csr_src[at] = s;
  csr_coef[at] = cf;
  int g = inv[dt] >> 8;
  atomicAdd(&Q[g * HH + s], cf * (1.0f / 256.0f));
}

// ---------------- time embedding (reads tw directly, writes out2 region) ----------------
__global__ __launch_bounds__(256) void k_time(const int* __restrict__ xm,
                                              const float* __restrict__ hour_emb,
                                              const float* __restrict__ wday_emb,
                                              const float* __restrict__ tw,
                                              const float* __restrict__ tcb,
                                              float* __restrict__ out) {
  int tid = threadIdx.x;
  int half = tid >> 7, o = tid & 127;
  int b = blockIdx.x * 2 + half;
  int n = b / TPP, tp = b % TPP;
  __shared__ float sL[2][512];
  for (int k = 0; k < 4; ++k) {
    int t = tp * 4 + k;
    int wd = xm[(n * TT + t) * 2 + 0];
    int hr = xm[(n * TT + t) * 2 + 1];
    sL[half][o * 4 + k] = hour_emb[hr * DD + o] + wday_emb[wd * DD + o];
  }
  __syncthreads();
  const float4* twv = (const float4*)(tw + (size_t)o * 512);
  const float4* sv = (const float4*)sL[half];
  float a0 = tcb[o], a1 = 0.f, a2 = 0.f, a3 = 0.f;
  for (int j = 0; j < 128; j += 4) {
    float4 w0 = twv[j + 0], w1 = twv[j + 1], w2 = twv[j + 2], w3 = twv[j + 3];
    float4 s0 = sv[j + 0], s1 = sv[j + 1], s2 = sv[j + 2], s3 = sv[j + 3];
    a0 = fmaf(s0.x, w0.x, a0); a0 = fmaf(s0.y, w0.y, a0);
    a0 = fmaf(s0.z, w0.z, a0); a0 = fmaf(s0.w, w0.w, a0);
    a1 = fmaf(s1.x, w1.x, a1); a1 = fmaf(s1.y, w1.y, a1);
    a1 = fmaf(s1.z, w1.z, a1); a1 = fmaf(s1.w, w1.w, a1);
    a2 = fmaf(s2.x, w2.x, a2); a2 = fmaf(s2.y, w2.y, a2);
    a2 = fmaf(s2.z, w2.z, a2); a2 = fmaf(s2.w, w2.w, a2);
    a3 = fmaf(s3.x, w3.x, a3); a3 = fmaf(s3.y, w3.y, a3);
    a3 = fmaf(s3.z, w3.z, a3); a3 = fmaf(s3.w, w3.w, a3);
  }
  float acc = (a0 + a1) + (a2 + a3);
  size_t base = (size_t)NOUT + ((size_t)n * TT + tp * 4) * DD + o;
  out[base] = acc;
  out[base + DD] = acc;
  out[base + 2 * DD] = acc;
  out[base + 3 * DD] = acc;
}

// ---------------- fused gather + conv-expand + MFMA GEMM, no global atomics ----------------
// Block = (quarter q, batch b): owns 256 h-rows, two 128x128x128 chunk GEMMs.
// LDS: W1T swizzled [0:32K), agg/x region [32K:64K), xbar 5K, yL 2K -> 72.7 KB, 2 blocks/CU.
__global__ __launch_bounds__(256, 2) void k_gemm(
    const float* __restrict__ x, const float* __restrict__ tcw,
    const float* __restrict__ tcb, const __hip_bfloat16* __restrict__ w1sw,
    const float* __restrict__ bias1, const int* __restrict__ row_ptr,
    const int* __restrict__ csr_src, const float* __restrict__ csr_coef,
    const float* __restrict__ Q, __hip_bfloat16* __restrict__ ypart) {
  __shared__ __align__(16) char uni[65536];
  __shared__ float xbarL[256 * 5];
  __shared__ float yL[512];
  char* Wr = uni;
  char* Gr = uni + 32768;
  int tid = threadIdx.x;
  int q = blockIdx.x;
  int b = blockIdx.y;
  int h0 = q * 256;
  int n_ = b / TPP, tp = b % TPP;

  // stage W1T (pre-swizzled -> linear copy) and x-patch (fp32 -> bf16 [s][k]) into Gr
  const uint4* wsrc = (const uint4*)w1sw;
  uint4* wdst = (uint4*)Wr;
  for (int i = tid; i < 2048; i += 256) wdst[i] = wsrc[i];
  const float* xb = x + ((size_t)n_ * TT + tp * 4) * HH;
  __hip_bfloat16* xp = (__hip_bfloat16*)Gr;
  for (int i = tid; i < 4096; i += 256) {
    int s = i & 1023, k = i >> 10;  // i = k*1024+s, coalesced read
    xp[s * 4 + k] = __float2bfloat16(xb[i]);
  }
  yL[tid] = 0.f;
  yL[tid + 256] = 0.f;

  // per-thread constants
  int dp = tid & 63;            // d-pair for A2
  int d0 = dp * 2;
  float twa0 = tcw[d0 * 4 + 0], twa1 = tcw[d0 * 4 + 1];
  float twa2 = tcw[d0 * 4 + 2], twa3 = tcw[d0 * 4 + 3];
  float twb0 = tcw[d0 * 4 + 4], twb1 = tcw[d0 * 4 + 5];
  float twb2 = tcw[d0 * 4 + 6], twb3 = tcw[d0 * 4 + 7];
  float tba = tcb[d0], tbb = tcb[d0 + 1];
  int lane = tid & 63, w = tid >> 6;
  int colq = lane & 15, quad = lane >> 4;
  float bias[8];
#pragma unroll
  for (int jn = 0; jn < 8; ++jn) bias[jn] = bias1[jn * 16 + colq];
  __syncthreads();

  // phase A: per-thread row gather; xbar[r][0..3]=sum cf*x4, [4]=sum cf
  {
    int h = h0 + tid;
    int j0 = row_ptr[h], j1 = row_ptr[h + 1];
    float a0 = 0.f, a1 = 0.f, a2 = 0.f, a3 = 0.f, cs = 0.f;
    const uint2* xu = (const uint2*)Gr;
    for (int j = j0; j < j1; ++j) {
      int s = csr_src[j];
      float cf = csr_coef[j];
      uint2 u = xu[s];
      union { unsigned i; float f; } t0, t1, t2, t3;
      t0.i = u.x << 16;
      t1.i = u.x & 0xffff0000u;
      t2.i = u.y << 16;
      t3.i = u.y & 0xffff0000u;
      a0 = fmaf(cf, t0.f, a0);
      a1 = fmaf(cf, t1.f, a1);
      a2 = fmaf(cf, t2.f, a2);
      a3 = fmaf(cf, t3.f, a3);
      cs += cf;
    }
    xbarL[tid * 5 + 0] = a0;
    xbarL[tid * 5 + 1] = a1;
    xbarL[tid * 5 + 2] = a2;
    xbarL[tid * 5 + 3] = a3;
    xbarL[tid * 5 + 4] = cs;
  }
  __syncthreads();

  float yacc[4][8];
#pragma unroll
  for (int g = 0; g < 4; ++g)
#pragma unroll
    for (int jn = 0; jn < 8; ++jn) yacc[g][jn] = 0.f;

  int gg = dp >> 2;
  for (int ch = 0; ch < 2; ++ch) {
    // A2: agg[row][d] = cs*tcb[d] + sum_k xbar[row][k]*tcw[d][k] -> bf16 swizzled in Gr
#pragma unroll 4
    for (int it = 0; it < 32; ++it) {
      int row = (tid >> 6) + it * 4;  // wave-uniform
      const float* xr = &xbarL[(ch * 128 + row) * 5];
      float x0 = xr[0], x1 = xr[1], x2 = xr[2], x3 = xr[3], xc = xr[4];
      float v0 = xc * tba;
      v0 = fmaf(x0, twa0, v0); v0 = fmaf(x1, twa1, v0);
      v0 = fmaf(x2, twa2, v0); v0 = fmaf(x3, twa3, v0);
      float v1 = xc * tbb;
      v1 = fmaf(x0, twb0, v1); v1 = fmaf(x1, twb1, v1);
      v1 = fmaf(x2, twb2, v1); v1 = fmaf(x3, twb3, v1);
      union { __hip_bfloat16 h[2]; unsigned u; } pk;
      pk.h[0] = __float2bfloat16(v0);
      pk.h[1] = __float2bfloat16(v1);
      *(unsigned*)(Gr + row * 256 + ((gg ^ (row & 7)) * 16) + (dp & 3) * 4) = pk.u;
    }
    __syncthreads();

    // GEMM 128x128x128: wave w -> m-tiles {2w,2w+1}, n-tiles 0..7
    f32x4 acc[2][8];
#pragma unroll
    for (int im = 0; im < 2; ++im)
#pragma unroll
      for (int jn = 0; jn < 8; ++jn) acc[im][jn] = (f32x4){0.f, 0.f, 0.f, 0.f};
#pragma unroll
    for (int kc = 0; kc < 4; ++kc) {
      bf16x8 afr[2], bfr[8];
#pragma unroll
      for (int im = 0; im < 2; ++im) {
        int row = (w * 2 + im) * 16 + colq;
        afr[im] = *(const bf16x8*)(Gr + row * 256 + (((kc * 4 + quad) ^ (row & 7)) * 16));
      }
#pragma unroll
      for (int jn = 0; jn < 8; ++jn) {
        int nr = jn * 16 + colq;
        bfr[jn] = *(const bf16x8*)(Wr + nr * 256 + (((kc * 4 + quad) ^ (nr & 7)) * 16));
      }
#pragma unroll
      for (int im = 0; im < 2; ++im)
#pragma unroll
        for (int jn = 0; jn < 8; ++jn)
          acc[im][jn] = __builtin_amdgcn_mfma_f32_16x16x32_bf16(afr[im], bfr[jn],
                                                                acc[im][jn], 0, 0, 0);
    }

    // epilogue: relu(+b1), Q-weighted accumulate into registers
#pragma unroll
    for (int im = 0; im < 2; ++im) {
      int rb = h0 + ch * 128 + (w * 2 + im) * 16 + quad * 4;
      float qg[4][4];
#pragma unroll
      for (int g = 0; g < 4; ++g)
#pragma unroll
        for (int reg = 0; reg < 4; ++reg) qg[g][reg] = Q[g * HH + rb + reg];
#pragma unroll
      for (int jn = 0; jn < 8; ++jn) {
        f32x4 c = acc[im][jn];
        float bo = bias[jn];
        float v0 = fmaxf(c[0] + bo, 0.f);
        float v1 = fmaxf(c[1] + bo, 0.f);
        float v2 = fmaxf(c[2] + bo, 0.f);
        float v3 = fmaxf(c[3] + bo, 0.f);
#pragma unroll
        for (int g = 0; g < 4; ++g) {
          float pg = qg[g][0] * v0 + qg[g][1] * v1;
          pg = fmaf(qg[g][2], v2, pg);
          pg = fmaf(qg[g][3], v3, pg);
          yacc[g][jn] += pg;
        }
      }
    }
    __syncthreads();  // Gr reads done before next chunk's A2 overwrite
  }

  // reduce yacc across quads (rows 16-apart lanes), then 8 LDS atomics/thread
#pragma unroll
  for (int g = 0; g < 4; ++g)
#pragma unroll
    for (int jn = 0; jn < 8; ++jn) {
      float v = yacc[g][jn];
      v += __shfl_xor(v, 16, 64);
      v += __shfl_xor(v, 32, 64);
      yacc[g][jn] = v;
    }
#pragma unroll
  for (int jn = 0; jn < 8; ++jn) {
    float vq = yacc[0][jn];
    if (quad == 1) vq = yacc[1][jn];
    if (quad == 2) vq = yacc[2][jn];
    if (quad == 3) vq = yacc[3][jn];
    atomicAdd(&yL[quad * DD + jn * 16 + colq], vq);  // distinct addr per lane; 4-wave contention only
  }
  __syncthreads();

  __hip_bfloat16* yp = ypart + ((size_t)q * BB + b) * 512;
  yp[tid] = __float2bfloat16(yL[tid]);
  yp[tid + 256] = __float2bfloat16(yL[tid + 256]);
}

// ---------------- epilogue: z = (sum_q ypart) @ W2 + b2; out = z + time ----------------
__global__ __launch_bounds__(128) void k_out(const __hip_bfloat16* __restrict__ ypart,
                                             const float* __restrict__ W2,
                                             const float* __restrict__ b2,
                                             float* __restrict__ out) {
  int bg = blockIdx.x;
  int b = bg >> 2, g = bg & 3;
  int n = b / TPP, tp = b % TPP;
  int o = threadIdx.x;
  __shared__ float yLoc[DD];
  float s = 0.f;
#pragma unroll
  for (int qq = 0; qq < 4; ++qq)
    s += bf2f(ypart[((size_t)qq * BB + b) * 512 + g * DD + o]);
  yLoc[o] = s;
  __syncthreads();
  float a0 = b2[o], a1 = 0.f, a2 = 0.f, a3 = 0.f;
  for (int d = 0; d < DD; d += 4) {
    a0 = fmaf(yLoc[d + 0], W2[(d + 0) * DD + o], a0);
    a1 = fmaf(yLoc[d + 1], W2[(d + 1) * DD + o], a1);
    a2 = fmaf(yLoc[d + 2], W2[(d + 2) * DD + o], a2);
    a3 = fmaf(yLoc[d + 3], W2[(d + 3) * DD + o], a3);
  }
  size_t oi = ((size_t)n * TT + tp * 4 + g) * DD + o;
  out[oi] = (a0 + a1) + (a2 + a3) + out[(size_t)NOUT + oi];
}

extern "C" void kernel_launch(void* const* d_in, const int* in_sizes, int n_in,
                              void* d_out, int out_size, void* d_ws, size_t ws_size,
                              hipStream_t stream) {
  const float* x = (const float*)d_in[0];
  const int* xm = (const int*)d_in[1];
  const int* edges = (const int*)d_in[2];
  const int* node_split = (const int*)d_in[3];
  const float* hour_emb = (const float*)d_in[4];
  const float* wday_emb = (const float*)d_in[5];
  const float* timeconv_w = (const float*)d_in[6];
  const float* timeconv_b = (const float*)d_in[7];
  const float* tcw = (const float*)d_in[8];
  const float* tcb = (const float*)d_in[9];
  const float* W1 = (const float*)d_in[10];
  const float* b1 = (const float*)d_in[11];
  const float* W2 = (const float*)d_in[12];
  const float* b2 = (const float*)d_in[13];
  float* out = (float*)d_out;

  char* w = (char*)d_ws;
  int* degE = (int*)(w + 0);                 //    4096 B (zeroed)
  int* fill = (int*)(w + 4096);              //    4096 B (zeroed)
  float* Q = (float*)(w + 8192);             //   16384 B (zeroed)
  size_t zbytes = 24576;
  int* row_ptr = (int*)(w + 24576);          //    4352 B
  int* inv = (int*)(w + 28928);              //    4096 B
  int* csr_src = (int*)(w + 33024);          //   69632 B
  float* csr_coef = (float*)(w + 102656);    //   69632 B
  __hip_bfloat16* w1sw = (__hip_bfloat16*)(w + 172288);   //   32768 B
  __hip_bfloat16* ypart = (__hip_bfloat16*)(w + 205056);  // 1572864 B (end ~1.74 MB)

  hipMemsetAsync(d_ws, 0, zbytes, stream);
  k_setup<<<68, 256, 0, stream>>>(edges, degE, node_split, inv, W1, w1sw);
  k_scan<<<1, 1024, 0, stream>>>(degE, row_ptr);
  k_scatter<<<68, 256, 0, stream>>>(edges, degE, row_ptr, inv, fill, csr_src, csr_coef, Q);
  k_time<<<BB / 2, 256, 0, stream>>>(xm, hour_emb, wday_emb, timeconv_w, timeconv_b, out);
  dim3 gmain(4, BB);
  k_gemm<<<gmain, 256, 0, stream>>>(x, tcw, tcb, w1sw, b1, row_ptr, csr_src, csr_coef, Q,
                                    ypart);
  k_out<<<BB * 4, 128, 0, stream>>>(ypart, W2, b2, out);
}